// Round 5
// baseline (476.472 us; speedup 1.0000x reference)
//
#include <hip/hip_runtime.h>
#include <cmath>

#define D 160
#define DD (D*D)          // 25600
#define NVOX (D*D*D)
#define BIGV (NVOX + 2)
#define NBINS 4096
#define HALF 16
#define RGRID 800         // rotate-pass blocks = DD/32, also hist partial count
#define SGRID 1000        // sweep blocks (512 thr, 8 cells/thread)
#define ZGRID 1000        // zero-cnt blocks fused into sweep 4
#define CGRID 800         // cand rider blocks fused into sweep 5

typedef int nt_i4 __attribute__((ext_vector_type(4)));

// ---------------------------------------------------------------------------
// Rotate box pass as a device block-function (512-thread mapping: 16 strips
// x 10 elems), so it can ride inside sweep launches as extra blocks.
// MODE 0: pack classes from raw float data. MODE 1: pass-through uint.
// Layout (a,b,c) c-contig -> filter along c -> write (c,a,b).
// ---------------------------------------------------------------------------
template<int MODE>
__device__ __forceinline__ void rot_block(
    const void* __restrict__ vin, unsigned* __restrict__ out, int bi, int tid)
{
    __shared__ unsigned tin[32][161];
    __shared__ unsigned filt[160][33];
    int L0 = bi * 32;
    size_t base = (size_t)L0 * D;

    if (MODE == 0) {
        const float4* s4 = (const float4*)((const float*)vin + base);
        for (int i = tid; i < 32 * (D / 4); i += 512) {
            float4 v = s4[i];
            int e = i * 4, r = e / D, c = e - r * D;
            float rr;
            rr = rintf(v.x); tin[r][c]   = (rr==0.f) | ((rr==1.f)?0x10000u:0u);
            rr = rintf(v.y); tin[r][c+1] = (rr==0.f) | ((rr==1.f)?0x10000u:0u);
            rr = rintf(v.z); tin[r][c+2] = (rr==0.f) | ((rr==1.f)?0x10000u:0u);
            rr = rintf(v.w); tin[r][c+3] = (rr==0.f) | ((rr==1.f)?0x10000u:0u);
        }
    } else {
        const uint4* s4 = (const uint4*)((const unsigned*)vin + base);
        for (int i = tid; i < 32 * (D / 4); i += 512) {
            uint4 v = s4[i];
            int e = i * 4, r = e / D, c = e - r * D;
            tin[r][c] = v.x; tin[r][c+1] = v.y; tin[r][c+2] = v.z; tin[r][c+3] = v.w;
        }
    }
    __syncthreads();

    {
        int r = tid & 31, s = tid >> 5;      // s in [0,16)
        int i0 = 10 * s;
        const unsigned* ln = tin[r];
        unsigned sum = 0u;
        int jlo = i0 - 16; if (jlo < 0) jlo = 0;
        int jhi = i0 + 15; if (jhi > D - 1) jhi = D - 1;
        for (int j = jlo; j <= jhi; ++j) sum += ln[j];
        #pragma unroll
        for (int k = 0; k < 10; ++k) {
            int i = i0 + k;
            filt[i][r] = sum;
            int add = i + 16, rem = i - 16;
            if (add <= D - 1) sum += ln[add];
            if (rem >= 0)     sum -= ln[rem];
        }
    }
    __syncthreads();

    int r = tid & 31;
    for (int c = (tid >> 5); c < D; c += 16)
        out[(size_t)c * DD + L0 + r] = filt[c][r];
}

// ---------------------------------------------------------------------------
// Rotate box filter, FLOAT path, pass 1: fuses the lsize*valid gather.
// ---------------------------------------------------------------------------
__global__ __launch_bounds__(256) void box_rot_f32_g_kernel(
    const int* __restrict__ lab, const int* __restrict__ cnt,
    const unsigned* __restrict__ cwp, float* __restrict__ out)
{
    __shared__ float tin[32][161];
    __shared__ float filt[160][33];
    int L0 = blockIdx.x * 32;
    size_t base = (size_t)L0 * D;

    const int4*  lab4 = (const int4*)(lab + base);
    const uint4* cw4  = (const uint4*)(cwp + base);
    for (int i = threadIdx.x; i < 32 * (D / 4); i += 256) {
        int4 l = lab4[i];
        uint4 cw = cw4[i];
        int e = i * 4, r = e / D, c = e - r * D;
        tin[r][c]   = (l.x != BIGV && (cw.x >> 16) > 100u) ? (float)cnt[l.x] : 0.f;
        tin[r][c+1] = (l.y != BIGV && (cw.y >> 16) > 100u) ? (float)cnt[l.y] : 0.f;
        tin[r][c+2] = (l.z != BIGV && (cw.z >> 16) > 100u) ? (float)cnt[l.z] : 0.f;
        tin[r][c+3] = (l.w != BIGV && (cw.w >> 16) > 100u) ? (float)cnt[l.w] : 0.f;
    }
    __syncthreads();

    {
        int r = threadIdx.x & 31, s = threadIdx.x >> 5;
        int i0 = 20 * s;
        const float* ln = tin[r];
        float sum = 0.f;
        int jlo = i0 - 16; if (jlo < 0) jlo = 0;
        int jhi = i0 + 15; if (jhi > D - 1) jhi = D - 1;
        for (int j = jlo; j <= jhi; ++j) sum += ln[j];
        #pragma unroll 4
        for (int k = 0; k < 20; ++k) {
            int i = i0 + k;
            filt[i][r] = sum;
            int add = i + 16, rem = i - 16;
            if (add <= D - 1) sum += ln[add];
            if (rem >= 0)     sum -= ln[rem];
        }
    }
    __syncthreads();

    int r = threadIdx.x & 31;
    for (int c = (threadIdx.x >> 5); c < D; c += 8)
        out[(size_t)c * DD + L0 + r] = filt[c][r];
}

// plain float middle pass
__global__ __launch_bounds__(256) void box_rot_f32_kernel(
    const float* __restrict__ fin, float* __restrict__ out)
{
    __shared__ float tin[32][161];
    __shared__ float filt[160][33];
    int L0 = blockIdx.x * 32;
    size_t base = (size_t)L0 * D;

    const float4* s4 = (const float4*)(fin + base);
    for (int i = threadIdx.x; i < 32 * (D / 4); i += 256) {
        float4 v = s4[i];
        int e = i * 4, r = e / D, c = e - r * D;
        tin[r][c] = v.x; tin[r][c+1] = v.y; tin[r][c+2] = v.z; tin[r][c+3] = v.w;
    }
    __syncthreads();

    {
        int r = threadIdx.x & 31, s = threadIdx.x >> 5;
        int i0 = 20 * s;
        const float* ln = tin[r];
        float sum = 0.f;
        int jlo = i0 - 16; if (jlo < 0) jlo = 0;
        int jhi = i0 + 15; if (jhi > D - 1) jhi = D - 1;
        for (int j = jlo; j <= jhi; ++j) sum += ln[j];
        #pragma unroll 4
        for (int k = 0; k < 20; ++k) {
            int i = i0 + k;
            filt[i][r] = sum;
            int add = i + 16, rem = i - 16;
            if (add <= D - 1) sum += ln[add];
            if (rem >= 0)     sum -= ln[rem];
        }
    }
    __syncthreads();

    int r = threadIdx.x & 31;
    for (int c = (threadIdx.x >> 5); c < D; c += 8)
        out[(size_t)c * DD + L0 + r] = filt[c][r];
}

// ---------------------------------------------------------------------------
// cs pass 3 fused with finalize (idx + LDS histogram) AND the hist
// reduce+post (last-16-blocks ticket scheme; removes the hist_rp slot).
// Deadlock-safety: a block spins only if its ticket >= RGRID-16, i.e. all
// other blocks already passed their atomic (retired or retiring) — no
// circular wait. Second ticket elects the single post block.
// ---------------------------------------------------------------------------
__global__ __launch_bounds__(256) void box_rot_fin_kernel(
    const float* __restrict__ fin, const unsigned* __restrict__ cwp,
    unsigned short* __restrict__ idxbuf, int* __restrict__ partial,
    int* __restrict__ hist, float* __restrict__ ph_full,
    float* __restrict__ Sout, int* __restrict__ tickets)
{
    __shared__ float tin[32][161];
    __shared__ float filt[160][33];
    __shared__ int lh[NBINS];
    for (int i = threadIdx.x; i < NBINS; i += 256) lh[i] = 0;

    int L0 = blockIdx.x * 32;
    size_t base = (size_t)L0 * D;
    const float4* s4 = (const float4*)(fin + base);
    for (int i = threadIdx.x; i < 32 * (D / 4); i += 256) {
        float4 v = s4[i];
        int e = i * 4, r = e / D, c = e - r * D;
        tin[r][c] = v.x; tin[r][c+1] = v.y; tin[r][c+2] = v.z; tin[r][c+3] = v.w;
    }
    __syncthreads();

    {
        int r = threadIdx.x & 31, s = threadIdx.x >> 5;
        int i0 = 20 * s;
        const float* ln = tin[r];
        float sum = 0.f;
        int jlo = i0 - 16; if (jlo < 0) jlo = 0;
        int jhi = i0 + 15; if (jhi > D - 1) jhi = D - 1;
        for (int j = jlo; j <= jhi; ++j) sum += ln[j];
        #pragma unroll 4
        for (int k = 0; k < 20; ++k) {
            int i = i0 + k;
            filt[i][r] = sum;
            int add = i + 16, rem = i - 16;
            if (add <= D - 1) sum += ln[add];
            if (rem >= 0)     sum -= ln[rem];
        }
    }
    __syncthreads();

    int r = threadIdx.x & 31;
    int L = L0 + r;
    int y = L / D, z = L - (L / D) * D;
    bool byz = (y >= HALF && y < D - HALF && z >= HALF && z < D - HALF);
    int wy = min(y + 15, D - 1) - max(y - 16, 0) + 1;
    int wz = min(z + 15, D - 1) - max(z - 16, 0) + 1;
    for (int c = (threadIdx.x >> 5); c < D; c += 8) {   // c == x
        int p = c * DD + L;
        unsigned pk = cwp[p];
        unsigned cw0 = pk & 0xFFFFu;
        unsigned cw1 = pk >> 16;
        int wx = min(c + 15, D - 1) - max(c - 16, 0) + 1;
        unsigned cw2 = (unsigned)(wx * wy * wz) - cw0 - cw1;
        float v0 = (cw0 > 100u) ? 1.f : 0.f;
        float v1 = (cw1 > 100u) ? 1.f : 0.f;
        float v2 = (cw2 > 100u) ? 1.f : 0.f;
        float border = (byz && c >= HALF && c < D - HALF) ? 1.f : 0.f;
        float cd = (border * v1 + v0 + v2 >= 2.f) ? 1.f : 0.f;
        float mean = (cw1 > 0u) ? filt[c][r] / fmaxf((float)cw1, 1.f) : 0.f;
        int idx = (int)rintf(cd * mean);    // round half-to-even == jnp.round
        idx = min(max(idx, 0), NBINS - 1);
        idxbuf[p] = (unsigned short)idx;
        if (idx != 0) atomicAdd(&lh[idx], 1);   // hist[0] never consumed
    }
    __syncthreads();
    int* po = partial + blockIdx.x * NBINS;
    for (int i = threadIdx.x; i < NBINS; i += 256) po[i] = lh[i];

    // ---- fused hist reduce+post ----
    __threadfence();
    __shared__ int myt;
    if (threadIdx.x == 0) myt = atomicAdd(&tickets[0], 1);
    __syncthreads();
    if (myt < RGRID - 16) return;

    // reducer block: wait for all partials, then reduce a 256-bin slice
    if (threadIdx.x == 0) {
        while (__hip_atomic_load(&tickets[0], __ATOMIC_RELAXED,
                                 __HIP_MEMORY_SCOPE_AGENT) < RGRID)
            __builtin_amdgcn_s_sleep(8);
    }
    __syncthreads();
    int g = myt - (RGRID - 16);          // 0..15
    int bin = g * 256 + threadIdx.x;
    int s = 0;
    #pragma unroll 4
    for (int b = 0; b < RGRID; ++b) s += partial[b * NBINS + bin];
    __hip_atomic_store(&hist[bin], s, __ATOMIC_RELAXED, __HIP_MEMORY_SCOPE_AGENT);
    __threadfence();
    __syncthreads();
    __shared__ int myt3;
    if (threadIdx.x == 0) myt3 = atomicAdd(&tickets[1], 1);
    __syncthreads();
    if (myt3 < 15) return;

    // single post block (bit-identical arithmetic to the old hist_post)
    int t = threadIdx.x;
    __shared__ float red[256];
    int hv[16];
    #pragma unroll
    for (int k = 0; k < 16; ++k)
        hv[k] = __hip_atomic_load(&hist[t + k * 256], __ATOMIC_RELAXED,
                                  __HIP_MEMORY_SCOPE_AGENT);

    float loc = 0.f;
    #pragma unroll
    for (int k = 0; k < 16; ++k) {
        int b = t + k * 256;
        if (b >= 1) loc += (float)hv[k];
    }
    red[t] = loc; __syncthreads();
    for (int o = 128; o > 0; o >>= 1) { if (t < o) red[t] += red[t + o]; __syncthreads(); }
    float numb = red[0]; __syncthreads();

    float rv[16];
    loc = 0.f;
    #pragma unroll
    for (int k = 0; k < 16; ++k) {
        int b = t + k * 256;
        float rr = 0.f;
        if (b >= 1) {
            int h = hv[k];
            if (h > 0) rr = numb / (float)h;
        }
        rv[k] = rr;
        loc += rr;
    }
    red[t] = loc; __syncthreads();
    for (int o = 128; o > 0; o >>= 1) { if (t < o) red[t] += red[t + o]; __syncthreads(); }
    float sumrec = red[0]; __syncthreads();
    float inv_sumrec = (sumrec > 0.f) ? 1.f / sumrec : 0.f;

    loc = 0.f;
    #pragma unroll
    for (int k = 0; k < 16; ++k) {
        int b = t + k * 256;
        float phv = (b >= 1) ? rv[k] * inv_sumrec : 0.f;
        ph_full[b] = phv;
        loc += phv * (float)hv[k];
    }
    red[t] = loc; __syncthreads();
    for (int o = 128; o > 0; o >>= 1) { if (t < o) red[t] += red[t + o]; __syncthreads(); }
    if (t == 0) Sout[0] = (red[0] > 0.f) ? red[0] : 1.f;
}

// ---------------------------------------------------------------------------
// CCL: 16 single-generation sweeps (R2: 2-gen register fusion = 2.8x a
// sweep, loses; 16 launches is the structure). R3: each launch slot costs
// ~6us wall -> riders fill idle sweep launches (g1-g3: cw rotate passes;
// g4: cnt+ticket zeroing; g5: cand). R5 experiment: NON-TEMPORAL dst
// stores. Theory (ii): per-XCD working set src 2MB + dst 2MB + halos >
// 4MB L2 -> dirty-eviction thrash makes the 54MB WRITE_SIZE real; nt
// stores keep dst out of L2 (writeback 54->~17MB at the cost of FETCH
// 8.8->~17MB). If WRITE_SIZE instead stays ~54 -> it's a counter artifact
// and nt reverts next round.
// XCD swizzle: each XCD owns a contiguous 20-plane x-slab.
// ---------------------------------------------------------------------------
__device__ __forceinline__ int min6(int c, int a, int b, int d, int e, int f, int g) {
    if (c == BIGV) return BIGV;
    return min(min(min(c, a), min(b, d)), min(min(e, f), g));
}

__device__ __forceinline__ int4 min7_run(int4 c, int lm, int rm,
                                         int4 ym, int4 yp, int4 xm, int4 xp) {
    int4 o;
    o.x = min6(c.x, lm,  c.y, ym.x, yp.x, xm.x, xp.x);
    o.y = min6(c.y, c.x, c.z, ym.y, yp.y, xm.y, xp.y);
    o.z = min6(c.z, c.y, c.w, ym.z, yp.z, xm.z, xp.z);
    o.w = min6(c.w, c.z, rm,  ym.w, yp.w, xm.w, xp.w);
    return o;
}

__device__ __forceinline__ void wave_count(int l, int lane, int* __restrict__ cnt) {
    unsigned long long remaining = __ballot(l != BIGV);
    while (remaining) {
        int leader = __ffsll((unsigned long long)remaining) - 1;
        int ll = __shfl(l, leader, 64);
        unsigned long long mm = __ballot(l == ll);
        if (lane == leader) atomicAdd(&cnt[ll], (int)__popcll(mm & remaining));
        remaining &= ~mm;
    }
}

__device__ __forceinline__ int4 cls4(float4 v, int p0) {
    int4 l;
    l.x = (rintf(v.x) == 1.f) ? (p0 + 1) : BIGV;
    l.y = (rintf(v.y) == 1.f) ? (p0 + 2) : BIGV;
    l.z = (rintf(v.z) == 1.f) ? (p0 + 3) : BIGV;
    l.w = (rintf(v.w) == 1.f) ? (p0 + 4) : BIGV;
    return l;
}

struct LabLd {
    const int* __restrict__ a;
    __device__ __forceinline__ int4 v(int p) const { return ((const int4*)a)[p >> 2]; }
    __device__ __forceinline__ int  s(int p) const { return a[p]; }
};
struct DataLd {
    const float* __restrict__ a;
    __device__ __forceinline__ int4 v(int p) const { return cls4(((const float4*)a)[p >> 2], p); }
    __device__ __forceinline__ int  s(int p) const { return (rintf(a[p]) == 1.f) ? (p + 1) : BIGV; }
};

template<typename LDT, int COUNT>
__device__ __forceinline__ void sweep_block(
    LDT ld, int* __restrict__ outp, int* __restrict__ cnt, int b, int tid)
{
    const int4 BIG4 = make_int4(BIGV, BIGV, BIGV, BIGV);
    int sb = (b & 7) * (SGRID / 8) + (b >> 3);   // XCD-contiguous x-slab
    int lane = tid & 63;
    int wv   = tid >> 6;
    int wbase = sb * 4096 + wv * 512;
    int pA = wbase + 4 * lane;
    int pB = pA + 256;

    int4 cA = ld.v(pA), cB = ld.v(pB);

    int zA = pA % D, zB = pB % D;
    int lmA = __shfl_up(cA.w, 1);
    int rmA = __shfl_down(cA.x, 1);
    int lmB = __shfl_up(cB.w, 1);
    int rmB = __shfl_down(cB.x, 1);
    int stA = __shfl(cB.x, 0, 64);   // voxel wbase+256 (A.lane63 right nbr)
    int stB = __shfl(cA.w, 63, 64);  // voxel wbase+255 (B.lane0 left nbr)
    if (lane == 63) rmA = stA;
    if (lane == 0)  lmB = stB;
    if (zA == 0)          lmA = BIGV;
    else if (lane == 0)   lmA = ld.s(pA - 1);
    if (zA == D - 4)      rmA = BIGV;
    if (zB == 0)          lmB = BIGV;
    if (zB == D - 4)      rmB = BIGV;
    else if (lane == 63)  rmB = ld.s(pB + 4);

    int rA = pA / D, yA = rA % D, xA = rA / D;
    int4 ylA = (yA > 0)     ? ld.v(pA - D)  : BIG4;
    int4 yhA = (yA < D - 1) ? ld.v(pA + D)  : BIG4;
    int4 xlA = (xA > 0)     ? ld.v(pA - DD) : BIG4;
    int4 xhA = (xA < D - 1) ? ld.v(pA + DD) : BIG4;
    int4 oA = min7_run(cA, lmA, rmA, ylA, yhA, xlA, xhA);

    int rB = pB / D, yB = rB % D, xB = rB / D;
    int4 ylB = (yB > 0)     ? ld.v(pB - D)  : BIG4;
    int4 yhB = (yB < D - 1) ? ld.v(pB + D)  : BIG4;
    int4 xlB = (xB > 0)     ? ld.v(pB - DD) : BIG4;
    int4 xhB = (xB < D - 1) ? ld.v(pB + DD) : BIG4;
    int4 oB = min7_run(cB, lmB, rmB, ylB, yhB, xlB, xhB);

    // non-temporal dst stores: keep dst out of L2 (see header comment)
    int4* out4 = (int4*)outp;
    __builtin_nontemporal_store(*(const nt_i4*)&oA, (nt_i4*)&out4[pA >> 2]);
    __builtin_nontemporal_store(*(const nt_i4*)&oB, (nt_i4*)&out4[pB >> 2]);

    if (COUNT) {   // final generation: component-size count from registers
        wave_count(oA.x, lane, cnt);
        wave_count(oA.y, lane, cnt);
        wave_count(oA.z, lane, cnt);
        wave_count(oA.w, lane, cnt);
        wave_count(oB.x, lane, cnt);
        wave_count(oB.y, lane, cnt);
        wave_count(oB.z, lane, cnt);
        wave_count(oB.w, lane, cnt);
    }
}

// plain sweeps (g6..g15)
__global__ __launch_bounds__(512) void ccl_sweep_kernel(
    const int* __restrict__ lab, int* __restrict__ outp)
{
    LabLd ld{lab};
    sweep_block<LabLd, 0>(ld, outp, nullptr, blockIdx.x, threadIdx.x);
}

// final sweep (g16) + component-size count
__global__ __launch_bounds__(512) void ccl_sweep_count_kernel(
    const int* __restrict__ lab, int* __restrict__ outp, int* __restrict__ cnt)
{
    LabLd ld{lab};
    sweep_block<LabLd, 1>(ld, outp, cnt, blockIdx.x, threadIdx.x);
}

// sweep + rotate pass fused (g1..g3). MODE0: sweep from data + rot pass1
// (pack classes from data). MODE1: sweep from labels + rot pass-through.
template<int MODE>
__global__ __launch_bounds__(512) void sweep_rot_kernel(
    const float* __restrict__ data, const int* __restrict__ labsrc,
    int* __restrict__ swdst,
    const void* __restrict__ rin, unsigned* __restrict__ rout)
{
    if ((int)blockIdx.x < SGRID) {
        if (MODE == 0) {
            DataLd ld{data};
            sweep_block<DataLd, 0>(ld, swdst, nullptr, blockIdx.x, threadIdx.x);
        } else {
            LabLd ld{labsrc};
            sweep_block<LabLd, 0>(ld, swdst, nullptr, blockIdx.x, threadIdx.x);
        }
    } else {
        rot_block<MODE>(rin, rout, blockIdx.x - SGRID, threadIdx.x);
    }
}

// sweep g4 + zero the cnt region and the tickets (W4 dead after g3 read
// it; must be zero before g16's atomics). Replaces the upfront memset.
__global__ __launch_bounds__(512) void sweep_zero_kernel(
    const int* __restrict__ labsrc, int* __restrict__ swdst,
    int* __restrict__ zbuf, int* __restrict__ tickets)
{
    if ((int)blockIdx.x < SGRID) {
        LabLd ld{labsrc};
        sweep_block<LabLd, 0>(ld, swdst, nullptr, blockIdx.x, threadIdx.x);
    } else {
        int zb = blockIdx.x - SGRID;                 // 0..ZGRID-1
        int t = (zb * 512 + threadIdx.x) * 2;        // int4 units
        const int4 z4 = make_int4(0, 0, 0, 0);
        ((int4*)zbuf)[t] = z4; ((int4*)zbuf)[t + 1] = z4;   // 1000*512*8 = NVOX ints
        if (zb == 0 && threadIdx.x == 0) {
            zbuf[NVOX] = 0; tickets[0] = 0; tickets[1] = 0;
        }
    }
}

// sweep g5 + cand rider: candidates depend only on cwp (ready after g3).
__global__ __launch_bounds__(512) void sweep_cand_kernel(
    const int* __restrict__ labsrc, int* __restrict__ swdst,
    const unsigned* __restrict__ cwp, float* __restrict__ cand)
{
    if ((int)blockIdx.x < SGRID) {
        LabLd ld{labsrc};
        sweep_block<LabLd, 0>(ld, swdst, nullptr, blockIdx.x, threadIdx.x);
        return;
    }
    int t0 = (blockIdx.x - SGRID) * 512 + threadIdx.x;
    const uint4* cw4 = (const uint4*)cwp;
    float4* c4 = (float4*)cand;
    for (int q = t0; q < NVOX / 4; q += CGRID * 512) {
        int p0 = q * 4;
        int z0 = p0 % D;
        int r  = p0 / D;
        int y  = r % D;
        int x  = r / D;
        int wy = min(y + 15, D - 1) - max(y - 16, 0) + 1;
        int wx = min(x + 15, D - 1) - max(x - 16, 0) + 1;
        bool bxy = (y >= HALF && y < D - HALF && x >= HALF && x < D - HALF);
        uint4 pk = cw4[q];
        float4 o;
        {
            unsigned c0 = pk.x & 0xFFFFu, c1 = pk.x >> 16;
            int z = z0, wz = min(z + 15, D - 1) - max(z - 16, 0) + 1;
            unsigned c2 = (unsigned)(wx * wy * wz) - c0 - c1;
            float v0 = (c0 > 100u) ? 1.f : 0.f, v1 = (c1 > 100u) ? 1.f : 0.f, v2 = (c2 > 100u) ? 1.f : 0.f;
            float border = (bxy && z >= HALF && z < D - HALF) ? 1.f : 0.f;
            o.x = (border * v1 + v0 + v2 >= 2.f) ? 1.f : 0.f;
        }
        {
            unsigned c0 = pk.y & 0xFFFFu, c1 = pk.y >> 16;
            int z = z0 + 1, wz = min(z + 15, D - 1) - max(z - 16, 0) + 1;
            unsigned c2 = (unsigned)(wx * wy * wz) - c0 - c1;
            float v0 = (c0 > 100u) ? 1.f : 0.f, v1 = (c1 > 100u) ? 1.f : 0.f, v2 = (c2 > 100u) ? 1.f : 0.f;
            float border = (bxy && z >= HALF && z < D - HALF) ? 1.f : 0.f;
            o.y = (border * v1 + v0 + v2 >= 2.f) ? 1.f : 0.f;
        }
        {
            unsigned c0 = pk.z & 0xFFFFu, c1 = pk.z >> 16;
            int z = z0 + 2, wz = min(z + 15, D - 1) - max(z - 16, 0) + 1;
            unsigned c2 = (unsigned)(wx * wy * wz) - c0 - c1;
            float v0 = (c0 > 100u) ? 1.f : 0.f, v1 = (c1 > 100u) ? 1.f : 0.f, v2 = (c2 > 100u) ? 1.f : 0.f;
            float border = (bxy && z >= HALF && z < D - HALF) ? 1.f : 0.f;
            o.z = (border * v1 + v0 + v2 >= 2.f) ? 1.f : 0.f;
        }
        {
            unsigned c0 = pk.w & 0xFFFFu, c1 = pk.w >> 16;
            int z = z0 + 3, wz = min(z + 15, D - 1) - max(z - 16, 0) + 1;
            unsigned c2 = (unsigned)(wx * wy * wz) - c0 - c1;
            float v0 = (c0 > 100u) ? 1.f : 0.f, v1 = (c1 > 100u) ? 1.f : 0.f, v2 = (c2 > 100u) ? 1.f : 0.f;
            float border = (bxy && z >= HALF && z < D - HALF) ? 1.f : 0.f;
            o.w = (border * v1 + v0 + v2 >= 2.f) ? 1.f : 0.f;
        }
        c4[q] = o;
    }
}

__global__ __launch_bounds__(256) void proba_kernel(
    const unsigned short* __restrict__ idxbuf,
    const float* __restrict__ ph_full, const float* __restrict__ Sv,
    float* __restrict__ outp)
{
    int t = blockIdx.x * blockDim.x + threadIdx.x;   // exact grid NVOX/4
    ushort4 i4 = ((const ushort4*)idxbuf)[t];
    float inv = 1.f / Sv[0];
    float4 o;
    o.x = ph_full[i4.x] * inv;
    o.y = ph_full[i4.y] * inv;
    o.z = ph_full[i4.z] * inv;
    o.w = ph_full[i4.w] * inv;
    ((float4*)outp)[t] = o;
}

// ---------------------------------------------------------------------------
extern "C" void kernel_launch(void* const* d_in, const int* in_sizes, int n_in,
                              void* d_out, int out_size, void* d_ws, size_t ws_size,
                              hipStream_t stream)
{
    const float* data = (const float*)d_in[0];
    float* out   = (float*)d_out;
    float* cand  = out;
    float* proba = out + NVOX;

    char* ws = (char*)d_ws;
    const size_t NB = (size_t)NVOX * sizeof(float);
    float* W1 = (float*)(ws);
    float* W2 = (float*)(ws + NB);
    float* W3 = (float*)(ws + 2 * NB);
    int*   W4 = (int*)(ws + 3 * NB);                   // cnt region / 3rd ping-pong buf
    int*   cnt  = W4;                                  // NVOX+1 ints (last int in pad)
    float* ph   = (float*)(ws + 4 * NB + 16);
    int*   hist = (int*)  (ws + 4 * NB + 16 + NBINS * 4);
    float* Sv   = (float*)(ws + 4 * NB + 16 + 2 * NBINS * 4);
    int*   tickets = (int*)(ws + 4 * NB + 16 + 2 * NBINS * 4 + 8);
    unsigned short* idxbuf = (unsigned short*)cnt;     // cnt dead after cs pass 1
    int* partial = (int*)W2;                           // W2 dead after cs pass 2

    dim3 rb(256), rg(RGRID);                     // 800 blocks (float rotate passes)
    dim3 sbk(512);
    dim3 sg(SGRID);                              // 1000 blocks (plain sweeps)
    dim3 srg(SGRID + RGRID);                     // 1800 blocks (sweep + rotate)
    dim3 szg(SGRID + ZGRID);                     // 2000 blocks (sweep + zero)
    dim3 scg(SGRID + CGRID);                     // 1800 blocks (sweep + cand)
    dim3 pb(256), pg(NVOX / 4 / 256);            // 4000 blocks (proba x4)

    // g1..g3: sweeps fused with the 3 independent cw int-rotate passes.
    // Sweeps ping-pong W2 -> W4 -> W2 (W4 = idle cnt region); rotates
    // data -> W1 -> W3 -> W1 (cwp ends in W1).
    sweep_rot_kernel<0><<<srg, sbk, 0, stream>>>(data, nullptr, (int*)W2,
                                                 data, (unsigned*)W1);       // g1 | rot1
    sweep_rot_kernel<1><<<srg, sbk, 0, stream>>>(nullptr, (int*)W2, W4,
                                                 W1, (unsigned*)W3);         // g2 | rot2
    sweep_rot_kernel<1><<<srg, sbk, 0, stream>>>(nullptr, W4, (int*)W2,
                                                 W3, (unsigned*)W1);         // g3 | rot3
    unsigned* cwp = (unsigned*)W1;               // original layout

    // g4: sweep fused with zeroing cnt + tickets (W4 dead after g3 read it).
    sweep_zero_kernel<<<szg, sbk, 0, stream>>>((int*)W2, (int*)W3, W4, tickets); // g4

    // g5: sweep fused with the cand rider (cand = f(cwp) only).
    sweep_cand_kernel<<<scg, sbk, 0, stream>>>((int*)W3, (int*)W2, cwp, cand);   // g5

    // g6..g15: plain sweeps, W2 <-> W3 ping-pong (g15 ends in W2).
    for (int i = 0; i < 10; ++i) {
        const int* src = (i & 1) ? (int*)W3 : (int*)W2;
        int*       dst = (i & 1) ? (int*)W2 : (int*)W3;
        ccl_sweep_kernel<<<sg, sbk, 0, stream>>>(src, dst);
    }
    // g16: final sweep + component-size count into cnt (=W4, zeroed at g4).
    ccl_sweep_count_kernel<<<sg, sbk, 0, stream>>>((int*)W2, (int*)W3, cnt);
    int* lab = (int*)W3;                         // gen-16 labels

    // cs float box sums (pass 1 fuses lsize*valid gather; pass 3 fuses
    // finalize: idx + histogram + reduce + post — cs, cd, hist_rp slot all
    // eliminated from the serial tail)
    box_rot_f32_g_kernel<<<rg, rb, 0, stream>>>(lab, cnt, cwp, W2);
    box_rot_f32_kernel<<<rg, rb, 0, stream>>>(W2, W3);
    box_rot_fin_kernel<<<rg, rb, 0, stream>>>(W3, cwp, idxbuf, partial,
                                              hist, ph, Sv, tickets);

    proba_kernel<<<pg, pb, 0, stream>>>(idxbuf, ph, Sv, proba);
}

// Round 6
// 394.006 us; speedup vs baseline: 1.2093x; 1.2093x over previous
//
#include <hip/hip_runtime.h>
#include <cmath>

#define D 160
#define DD (D*D)          // 25600
#define NVOX (D*D*D)
#define BIGV (NVOX + 2)
#define NBINS 4096
#define HALF 16
#define RGRID 800         // int rotate rider blocks = DD/32
#define FGRID 800         // fin blocks: 160 y x 5 z-tiles (also partial count)
#define SGRID 1000        // sweep blocks (512 thr, 8 cells/thread)
#define ZGRID 1000        // zero-cnt blocks fused into sweep 4
#define CGRID 800         // cand rider blocks fused into sweep 5

// ---------------------------------------------------------------------------
// Rotate box pass as a device block-function (512-thread mapping: 16 strips
// x 10 elems), riding inside sweep launches g1-g3 as extra blocks.
// MODE 0: pack classes from raw float data. MODE 1: pass-through uint.
// Layout (a,b,c) c-contig -> filter along c -> write (c,a,b).
// ---------------------------------------------------------------------------
template<int MODE>
__device__ __forceinline__ void rot_block(
    const void* __restrict__ vin, unsigned* __restrict__ out, int bi, int tid)
{
    __shared__ unsigned tin[32][161];
    __shared__ unsigned filt[160][33];
    int L0 = bi * 32;
    size_t base = (size_t)L0 * D;

    if (MODE == 0) {
        const float4* s4 = (const float4*)((const float*)vin + base);
        for (int i = tid; i < 32 * (D / 4); i += 512) {
            float4 v = s4[i];
            int e = i * 4, r = e / D, c = e - r * D;
            float rr;
            rr = rintf(v.x); tin[r][c]   = (rr==0.f) | ((rr==1.f)?0x10000u:0u);
            rr = rintf(v.y); tin[r][c+1] = (rr==0.f) | ((rr==1.f)?0x10000u:0u);
            rr = rintf(v.z); tin[r][c+2] = (rr==0.f) | ((rr==1.f)?0x10000u:0u);
            rr = rintf(v.w); tin[r][c+3] = (rr==0.f) | ((rr==1.f)?0x10000u:0u);
        }
    } else {
        const uint4* s4 = (const uint4*)((const unsigned*)vin + base);
        for (int i = tid; i < 32 * (D / 4); i += 512) {
            uint4 v = s4[i];
            int e = i * 4, r = e / D, c = e - r * D;
            tin[r][c] = v.x; tin[r][c+1] = v.y; tin[r][c+2] = v.z; tin[r][c+3] = v.w;
        }
    }
    __syncthreads();

    {
        int r = tid & 31, s = tid >> 5;      // s in [0,16)
        int i0 = 10 * s;
        const unsigned* ln = tin[r];
        unsigned sum = 0u;
        int jlo = i0 - 16; if (jlo < 0) jlo = 0;
        int jhi = i0 + 15; if (jhi > D - 1) jhi = D - 1;
        for (int j = jlo; j <= jhi; ++j) sum += ln[j];
        #pragma unroll
        for (int k = 0; k < 10; ++k) {
            int i = i0 + k;
            filt[i][r] = sum;
            int add = i + 16, rem = i - 16;
            if (add <= D - 1) sum += ln[add];
            if (rem >= 0)     sum -= ln[rem];
        }
    }
    __syncthreads();

    int r = tid & 31;
    for (int c = (tid >> 5); c < D; c += 16)
        out[(size_t)c * DD + L0 + r] = filt[c][r];
}

// ---------------------------------------------------------------------------
// Fused z+y float box pass over a whole x-plane (103 KB LDS, 1 block/CU;
// static LDS >64KB is gfx950-verified). Replaces box_rot_f32_g +
// box_rot_f32: one slot and one 33 MB round-trip removed. Gather fused.
// Stage 1: in-place prefix along z (sequential per row, safe). Stage 2:
// sliding y-window of w(y)=P[zhi]-P[zlo] computed on the fly (no second
// buffer). Output stays (x,y,z) layout, coalesced. fp order = cumsum-diff,
// same class as the reference's own _box1d.
// ---------------------------------------------------------------------------
__global__ __launch_bounds__(256) void plane_zy_g_kernel(
    const int* __restrict__ lab, const int* __restrict__ cnt,
    const unsigned* __restrict__ cwp, float* __restrict__ out)
{
    __shared__ float tin[160][161];   // 103,040 B
    int x = blockIdx.x;
    size_t base = (size_t)x * DD;
    const int4*  lab4 = (const int4*)(lab + base);
    const uint4* cw4  = (const uint4*)(cwp + base);
    for (int i = threadIdx.x; i < DD / 4; i += 256) {
        int4 l = lab4[i];
        uint4 cw = cw4[i];
        int e = i * 4, y = e / D, z = e - y * D;
        tin[y][z]   = (l.x != BIGV && (cw.x >> 16) > 100u) ? (float)cnt[l.x] : 0.f;
        tin[y][z+1] = (l.y != BIGV && (cw.y >> 16) > 100u) ? (float)cnt[l.y] : 0.f;
        tin[y][z+2] = (l.z != BIGV && (cw.z >> 16) > 100u) ? (float)cnt[l.z] : 0.f;
        tin[y][z+3] = (l.w != BIGV && (cw.w >> 16) > 100u) ? (float)cnt[l.w] : 0.f;
    }
    __syncthreads();

    if (threadIdx.x < D) {            // stage 1: prefix along z, 1 thr/row
        float p = 0.f;
        float* row = tin[threadIdx.x];
        for (int z = 0; z < D; ++z) { p += row[z]; row[z] = p; }
    }
    __syncthreads();

    if (threadIdx.x < D) {            // stage 2: y-window, 1 thr/column
        int c = threadIdx.x;
        int zhi = min(c + 15, D - 1);
        bool hl = (c >= 16);
        int zlo = c - 16;
        float* op = out + base + c;
        float S = 0.f;
        for (int u = 0; u <= 15; ++u)
            S += tin[u][zhi] - (hl ? tin[u][zlo] : 0.f);
        for (int y = 0; y < D; ++y) {
            op[(size_t)y * D] = S;
            int add = y + 16, rem = y - 16;
            if (add <= D - 1) S += tin[add][zhi] - (hl ? tin[add][zlo] : 0.f);
            if (rem >= 0)     S -= tin[rem][zhi] - (hl ? tin[rem][zlo] : 0.f);
        }
    }
}

// ---------------------------------------------------------------------------
// x-filter + finalize: per (y, z-tile) block, tile[x][zi] loaded via
// z-contiguous float4; x-slide with INLINE finalize (no filt array).
// LDS 37.5 KB (was 59) -> 4 blocks/CU. idx + LDS histogram -> partial.
// hist reduce+post stays a separate kernel (R5 lesson: device-fence +
// cross-XCD consumer INSIDE a wide kernel costs ~90us; the kernel
// boundary is the cheap L2 flush).
// ---------------------------------------------------------------------------
__global__ __launch_bounds__(256) void box_fin_x_kernel(
    const float* __restrict__ zy, const unsigned* __restrict__ cwp,
    unsigned short* __restrict__ idxbuf, int* __restrict__ partial)
{
    __shared__ float tile[160][33];
    __shared__ int lh[NBINS];
    for (int i = threadIdx.x; i < NBINS; i += 256) lh[i] = 0;

    int b = blockIdx.x;
    int y  = b % D;                   // 0..159
    int zt = b / D;                   // 0..4
    int z0 = zt * 32;
    int yb = y * D + z0;

    for (int i = threadIdx.x; i < D * 8; i += 256) {
        int x = i >> 3, q = i & 7;
        float4 v = *(const float4*)(zy + (size_t)x * DD + yb + q * 4);
        int c = q * 4;
        tile[x][c] = v.x; tile[x][c+1] = v.y; tile[x][c+2] = v.z; tile[x][c+3] = v.w;
    }
    __syncthreads();

    int r = threadIdx.x & 31;         // zi
    int s = threadIdx.x >> 5;         // x-segment 0..7
    int z = z0 + r;
    int i0 = 20 * s;
    bool byz = (y >= HALF && y < D - HALF && z >= HALF && z < D - HALF);
    int wy = min(y + 15, D - 1) - max(y - 16, 0) + 1;
    int wz = min(z + 15, D - 1) - max(z - 16, 0) + 1;

    float S = 0.f;
    int jlo = i0 - 16; if (jlo < 0) jlo = 0;
    int jhi = i0 + 15; if (jhi > D - 1) jhi = D - 1;
    for (int j = jlo; j <= jhi; ++j) S += tile[j][r];

    #pragma unroll 4
    for (int k = 0; k < 20; ++k) {
        int i = i0 + k;               // x
        int p = i * DD + y * D + z;
        unsigned pk = cwp[p];
        unsigned cw0 = pk & 0xFFFFu;
        unsigned cw1 = pk >> 16;
        int wx = min(i + 15, D - 1) - max(i - 16, 0) + 1;
        unsigned cw2 = (unsigned)(wx * wy * wz) - cw0 - cw1;
        float v0 = (cw0 > 100u) ? 1.f : 0.f;
        float v1 = (cw1 > 100u) ? 1.f : 0.f;
        float v2 = (cw2 > 100u) ? 1.f : 0.f;
        float border = (byz && i >= HALF && i < D - HALF) ? 1.f : 0.f;
        float cd = (border * v1 + v0 + v2 >= 2.f) ? 1.f : 0.f;
        float mean = (cw1 > 0u) ? S / fmaxf((float)cw1, 1.f) : 0.f;
        int idx = (int)rintf(cd * mean);    // round half-to-even == jnp.round
        idx = min(max(idx, 0), NBINS - 1);
        idxbuf[p] = (unsigned short)idx;
        if (idx != 0) atomicAdd(&lh[idx], 1);   // hist[0] never consumed

        int add = i + 16, rem = i - 16;
        if (add <= D - 1) S += tile[add][r];
        if (rem >= 0)     S -= tile[rem][r];
    }
    __syncthreads();
    int* po = partial + blockIdx.x * NBINS;
    for (int i = threadIdx.x; i < NBINS; i += 256) po[i] = lh[i];
}

// ---------------------------------------------------------------------------
// CCL: 16 single-generation sweeps (R2: 2-gen register fusion = 3.5x a
// sweep, loses; 16 launches is the structure). R3: each launch slot costs
// ~6us wall -> riders fill idle sweep launches (g1-g3: cw rotate passes;
// g4: cnt+ticket zeroing; g5: cand). R5: nt dst stores = neutral (reverted;
// 54MB WRITE_SIZE filed as artifact-or-unactionable). Plain int4 stores.
// XCD swizzle: each XCD owns a contiguous 20-plane x-slab.
// ---------------------------------------------------------------------------
__device__ __forceinline__ int min6(int c, int a, int b, int d, int e, int f, int g) {
    if (c == BIGV) return BIGV;
    return min(min(min(c, a), min(b, d)), min(min(e, f), g));
}

__device__ __forceinline__ int4 min7_run(int4 c, int lm, int rm,
                                         int4 ym, int4 yp, int4 xm, int4 xp) {
    int4 o;
    o.x = min6(c.x, lm,  c.y, ym.x, yp.x, xm.x, xp.x);
    o.y = min6(c.y, c.x, c.z, ym.y, yp.y, xm.y, xp.y);
    o.z = min6(c.z, c.y, c.w, ym.z, yp.z, xm.z, xp.z);
    o.w = min6(c.w, c.z, rm,  ym.w, yp.w, xm.w, xp.w);
    return o;
}

__device__ __forceinline__ void wave_count(int l, int lane, int* __restrict__ cnt) {
    unsigned long long remaining = __ballot(l != BIGV);
    while (remaining) {
        int leader = __ffsll((unsigned long long)remaining) - 1;
        int ll = __shfl(l, leader, 64);
        unsigned long long mm = __ballot(l == ll);
        if (lane == leader) atomicAdd(&cnt[ll], (int)__popcll(mm & remaining));
        remaining &= ~mm;
    }
}

__device__ __forceinline__ int4 cls4(float4 v, int p0) {
    int4 l;
    l.x = (rintf(v.x) == 1.f) ? (p0 + 1) : BIGV;
    l.y = (rintf(v.y) == 1.f) ? (p0 + 2) : BIGV;
    l.z = (rintf(v.z) == 1.f) ? (p0 + 3) : BIGV;
    l.w = (rintf(v.w) == 1.f) ? (p0 + 4) : BIGV;
    return l;
}

struct LabLd {
    const int* __restrict__ a;
    __device__ __forceinline__ int4 v(int p) const { return ((const int4*)a)[p >> 2]; }
    __device__ __forceinline__ int  s(int p) const { return a[p]; }
};
struct DataLd {
    const float* __restrict__ a;
    __device__ __forceinline__ int4 v(int p) const { return cls4(((const float4*)a)[p >> 2], p); }
    __device__ __forceinline__ int  s(int p) const { return (rintf(a[p]) == 1.f) ? (p + 1) : BIGV; }
};

template<typename LDT, int COUNT>
__device__ __forceinline__ void sweep_block(
    LDT ld, int* __restrict__ outp, int* __restrict__ cnt, int b, int tid)
{
    const int4 BIG4 = make_int4(BIGV, BIGV, BIGV, BIGV);
    int sb = (b & 7) * (SGRID / 8) + (b >> 3);   // XCD-contiguous x-slab
    int lane = tid & 63;
    int wv   = tid >> 6;
    int wbase = sb * 4096 + wv * 512;
    int pA = wbase + 4 * lane;
    int pB = pA + 256;

    int4 cA = ld.v(pA), cB = ld.v(pB);

    int zA = pA % D, zB = pB % D;
    int lmA = __shfl_up(cA.w, 1);
    int rmA = __shfl_down(cA.x, 1);
    int lmB = __shfl_up(cB.w, 1);
    int rmB = __shfl_down(cB.x, 1);
    int stA = __shfl(cB.x, 0, 64);   // voxel wbase+256 (A.lane63 right nbr)
    int stB = __shfl(cA.w, 63, 64);  // voxel wbase+255 (B.lane0 left nbr)
    if (lane == 63) rmA = stA;
    if (lane == 0)  lmB = stB;
    if (zA == 0)          lmA = BIGV;
    else if (lane == 0)   lmA = ld.s(pA - 1);
    if (zA == D - 4)      rmA = BIGV;
    if (zB == 0)          lmB = BIGV;
    if (zB == D - 4)      rmB = BIGV;
    else if (lane == 63)  rmB = ld.s(pB + 4);

    int rA = pA / D, yA = rA % D, xA = rA / D;
    int4 ylA = (yA > 0)     ? ld.v(pA - D)  : BIG4;
    int4 yhA = (yA < D - 1) ? ld.v(pA + D)  : BIG4;
    int4 xlA = (xA > 0)     ? ld.v(pA - DD) : BIG4;
    int4 xhA = (xA < D - 1) ? ld.v(pA + DD) : BIG4;
    int4 oA = min7_run(cA, lmA, rmA, ylA, yhA, xlA, xhA);

    int rB = pB / D, yB = rB % D, xB = rB / D;
    int4 ylB = (yB > 0)     ? ld.v(pB - D)  : BIG4;
    int4 yhB = (yB < D - 1) ? ld.v(pB + D)  : BIG4;
    int4 xlB = (xB > 0)     ? ld.v(pB - DD) : BIG4;
    int4 xhB = (xB < D - 1) ? ld.v(pB + DD) : BIG4;
    int4 oB = min7_run(cB, lmB, rmB, ylB, yhB, xlB, xhB);

    int4* out4 = (int4*)outp;
    out4[pA >> 2] = oA; out4[pB >> 2] = oB;

    if (COUNT) {   // final generation: component-size count from registers
        wave_count(oA.x, lane, cnt);
        wave_count(oA.y, lane, cnt);
        wave_count(oA.z, lane, cnt);
        wave_count(oA.w, lane, cnt);
        wave_count(oB.x, lane, cnt);
        wave_count(oB.y, lane, cnt);
        wave_count(oB.z, lane, cnt);
        wave_count(oB.w, lane, cnt);
    }
}

// plain sweeps (g6..g15)
__global__ __launch_bounds__(512) void ccl_sweep_kernel(
    const int* __restrict__ lab, int* __restrict__ outp)
{
    LabLd ld{lab};
    sweep_block<LabLd, 0>(ld, outp, nullptr, blockIdx.x, threadIdx.x);
}

// final sweep (g16) + component-size count
__global__ __launch_bounds__(512) void ccl_sweep_count_kernel(
    const int* __restrict__ lab, int* __restrict__ outp, int* __restrict__ cnt)
{
    LabLd ld{lab};
    sweep_block<LabLd, 1>(ld, outp, cnt, blockIdx.x, threadIdx.x);
}

// sweep + rotate pass fused (g1..g3). MODE0: sweep from data + rot pass1
// (pack classes from data). MODE1: sweep from labels + rot pass-through.
template<int MODE>
__global__ __launch_bounds__(512) void sweep_rot_kernel(
    const float* __restrict__ data, const int* __restrict__ labsrc,
    int* __restrict__ swdst,
    const void* __restrict__ rin, unsigned* __restrict__ rout)
{
    if ((int)blockIdx.x < SGRID) {
        if (MODE == 0) {
            DataLd ld{data};
            sweep_block<DataLd, 0>(ld, swdst, nullptr, blockIdx.x, threadIdx.x);
        } else {
            LabLd ld{labsrc};
            sweep_block<LabLd, 0>(ld, swdst, nullptr, blockIdx.x, threadIdx.x);
        }
    } else {
        rot_block<MODE>(rin, rout, blockIdx.x - SGRID, threadIdx.x);
    }
}

// sweep g4 + zero the cnt region and the tickets (W4 dead after g3 read
// it; must be zero before g16's atomics). Replaces the upfront memset.
__global__ __launch_bounds__(512) void sweep_zero_kernel(
    const int* __restrict__ labsrc, int* __restrict__ swdst,
    int* __restrict__ zbuf, int* __restrict__ tickets)
{
    if ((int)blockIdx.x < SGRID) {
        LabLd ld{labsrc};
        sweep_block<LabLd, 0>(ld, swdst, nullptr, blockIdx.x, threadIdx.x);
    } else {
        int zb = blockIdx.x - SGRID;                 // 0..ZGRID-1
        int t = (zb * 512 + threadIdx.x) * 2;        // int4 units
        const int4 z4 = make_int4(0, 0, 0, 0);
        ((int4*)zbuf)[t] = z4; ((int4*)zbuf)[t + 1] = z4;   // 1000*512*8 = NVOX ints
        if (zb == 0 && threadIdx.x == 0) {
            zbuf[NVOX] = 0; tickets[0] = 0; tickets[1] = 0;
        }
    }
}

// sweep g5 + cand rider: candidates depend only on cwp (ready after g3).
__global__ __launch_bounds__(512) void sweep_cand_kernel(
    const int* __restrict__ labsrc, int* __restrict__ swdst,
    const unsigned* __restrict__ cwp, float* __restrict__ cand)
{
    if ((int)blockIdx.x < SGRID) {
        LabLd ld{labsrc};
        sweep_block<LabLd, 0>(ld, swdst, nullptr, blockIdx.x, threadIdx.x);
        return;
    }
    int t0 = (blockIdx.x - SGRID) * 512 + threadIdx.x;
    const uint4* cw4 = (const uint4*)cwp;
    float4* c4 = (float4*)cand;
    for (int q = t0; q < NVOX / 4; q += CGRID * 512) {
        int p0 = q * 4;
        int z0 = p0 % D;
        int r  = p0 / D;
        int y  = r % D;
        int x  = r / D;
        int wy = min(y + 15, D - 1) - max(y - 16, 0) + 1;
        int wx = min(x + 15, D - 1) - max(x - 16, 0) + 1;
        bool bxy = (y >= HALF && y < D - HALF && x >= HALF && x < D - HALF);
        uint4 pk = cw4[q];
        float4 o;
        {
            unsigned c0 = pk.x & 0xFFFFu, c1 = pk.x >> 16;
            int z = z0, wz = min(z + 15, D - 1) - max(z - 16, 0) + 1;
            unsigned c2 = (unsigned)(wx * wy * wz) - c0 - c1;
            float v0 = (c0 > 100u) ? 1.f : 0.f, v1 = (c1 > 100u) ? 1.f : 0.f, v2 = (c2 > 100u) ? 1.f : 0.f;
            float border = (bxy && z >= HALF && z < D - HALF) ? 1.f : 0.f;
            o.x = (border * v1 + v0 + v2 >= 2.f) ? 1.f : 0.f;
        }
        {
            unsigned c0 = pk.y & 0xFFFFu, c1 = pk.y >> 16;
            int z = z0 + 1, wz = min(z + 15, D - 1) - max(z - 16, 0) + 1;
            unsigned c2 = (unsigned)(wx * wy * wz) - c0 - c1;
            float v0 = (c0 > 100u) ? 1.f : 0.f, v1 = (c1 > 100u) ? 1.f : 0.f, v2 = (c2 > 100u) ? 1.f : 0.f;
            float border = (bxy && z >= HALF && z < D - HALF) ? 1.f : 0.f;
            o.y = (border * v1 + v0 + v2 >= 2.f) ? 1.f : 0.f;
        }
        {
            unsigned c0 = pk.z & 0xFFFFu, c1 = pk.z >> 16;
            int z = z0 + 2, wz = min(z + 15, D - 1) - max(z - 16, 0) + 1;
            unsigned c2 = (unsigned)(wx * wy * wz) - c0 - c1;
            float v0 = (c0 > 100u) ? 1.f : 0.f, v1 = (c1 > 100u) ? 1.f : 0.f, v2 = (c2 > 100u) ? 1.f : 0.f;
            float border = (bxy && z >= HALF && z < D - HALF) ? 1.f : 0.f;
            o.z = (border * v1 + v0 + v2 >= 2.f) ? 1.f : 0.f;
        }
        {
            unsigned c0 = pk.w & 0xFFFFu, c1 = pk.w >> 16;
            int z = z0 + 3, wz = min(z + 15, D - 1) - max(z - 16, 0) + 1;
            unsigned c2 = (unsigned)(wx * wy * wz) - c0 - c1;
            float v0 = (c0 > 100u) ? 1.f : 0.f, v1 = (c1 > 100u) ? 1.f : 0.f, v2 = (c2 > 100u) ? 1.f : 0.f;
            float border = (bxy && z >= HALF && z < D - HALF) ? 1.f : 0.f;
            o.w = (border * v1 + v0 + v2 >= 2.f) ? 1.f : 0.f;
        }
        c4[q] = o;
    }
}

// ---------------------------------------------------------------------------
// hist reduce + post fused via last-block ticket (R4 version: separate
// 16-block kernel AFTER fin's kernel-end L2 flush — the safe structure).
// ---------------------------------------------------------------------------
__global__ __launch_bounds__(256) void hist_rp_kernel(
    const int* __restrict__ partial, int* __restrict__ hist,
    float* __restrict__ ph_full, float* __restrict__ Sout,
    int* __restrict__ ticket)
{
    int t = threadIdx.x;
    int bin = blockIdx.x * 256 + t;     // 16 x 256 = 4096
    int s = 0;
    #pragma unroll 4
    for (int b = 0; b < FGRID; ++b) s += partial[b * NBINS + bin];
    __hip_atomic_store(&hist[bin], s, __ATOMIC_RELAXED, __HIP_MEMORY_SCOPE_AGENT);
    __threadfence();
    __syncthreads();
    __shared__ int lastblk;
    if (t == 0) lastblk = (atomicAdd(ticket, 1) == gridDim.x - 1) ? 1 : 0;
    __syncthreads();
    if (!lastblk) return;

    // ---- post phase (one block), bit-identical arithmetic to hist_post ----
    __shared__ float red[256];
    int hv[16];
    #pragma unroll
    for (int k = 0; k < 16; ++k)
        hv[k] = __hip_atomic_load(&hist[t + k * 256], __ATOMIC_RELAXED,
                                  __HIP_MEMORY_SCOPE_AGENT);

    float loc = 0.f;
    #pragma unroll
    for (int k = 0; k < 16; ++k) {
        int b = t + k * 256;
        if (b >= 1) loc += (float)hv[k];
    }
    red[t] = loc; __syncthreads();
    for (int o = 128; o > 0; o >>= 1) { if (t < o) red[t] += red[t + o]; __syncthreads(); }
    float numb = red[0]; __syncthreads();

    float rv[16];
    loc = 0.f;
    #pragma unroll
    for (int k = 0; k < 16; ++k) {
        int b = t + k * 256;
        float r = 0.f;
        if (b >= 1) {
            int h = hv[k];
            if (h > 0) r = numb / (float)h;
        }
        rv[k] = r;
        loc += r;
    }
    red[t] = loc; __syncthreads();
    for (int o = 128; o > 0; o >>= 1) { if (t < o) red[t] += red[t + o]; __syncthreads(); }
    float sumrec = red[0]; __syncthreads();
    float inv_sumrec = (sumrec > 0.f) ? 1.f / sumrec : 0.f;

    loc = 0.f;
    #pragma unroll
    for (int k = 0; k < 16; ++k) {
        int b = t + k * 256;
        float ph = (b >= 1) ? rv[k] * inv_sumrec : 0.f;
        ph_full[b] = ph;
        loc += ph * (float)hv[k];
    }
    red[t] = loc; __syncthreads();
    for (int o = 128; o > 0; o >>= 1) { if (t < o) red[t] += red[t + o]; __syncthreads(); }
    if (t == 0) Sout[0] = (red[0] > 0.f) ? red[0] : 1.f;
}

__global__ __launch_bounds__(256) void proba_kernel(
    const unsigned short* __restrict__ idxbuf,
    const float* __restrict__ ph_full, const float* __restrict__ Sv,
    float* __restrict__ outp)
{
    int t = blockIdx.x * blockDim.x + threadIdx.x;   // exact grid NVOX/4
    ushort4 i4 = ((const ushort4*)idxbuf)[t];
    float inv = 1.f / Sv[0];
    float4 o;
    o.x = ph_full[i4.x] * inv;
    o.y = ph_full[i4.y] * inv;
    o.z = ph_full[i4.z] * inv;
    o.w = ph_full[i4.w] * inv;
    ((float4*)outp)[t] = o;
}

// ---------------------------------------------------------------------------
extern "C" void kernel_launch(void* const* d_in, const int* in_sizes, int n_in,
                              void* d_out, int out_size, void* d_ws, size_t ws_size,
                              hipStream_t stream)
{
    const float* data = (const float*)d_in[0];
    float* out   = (float*)d_out;
    float* cand  = out;
    float* proba = out + NVOX;

    char* ws = (char*)d_ws;
    const size_t NB = (size_t)NVOX * sizeof(float);
    float* W1 = (float*)(ws);
    float* W2 = (float*)(ws + NB);
    float* W3 = (float*)(ws + 2 * NB);
    int*   W4 = (int*)(ws + 3 * NB);                   // cnt region / 3rd ping-pong buf
    int*   cnt  = W4;                                  // NVOX+1 ints (last int in pad)
    float* ph   = (float*)(ws + 4 * NB + 16);
    int*   hist = (int*)  (ws + 4 * NB + 16 + NBINS * 4);
    float* Sv   = (float*)(ws + 4 * NB + 16 + 2 * NBINS * 4);
    int*   tickets = (int*)(ws + 4 * NB + 16 + 2 * NBINS * 4 + 8);
    unsigned short* idxbuf = (unsigned short*)cnt;     // cnt dead after plane_g
    int* partial = (int*)W3;                           // W3 (lab) dead after plane_g

    dim3 sbk(512);
    dim3 sg(SGRID);                              // 1000 blocks (plain sweeps)
    dim3 srg(SGRID + RGRID);                     // 1800 blocks (sweep + rotate)
    dim3 szg(SGRID + ZGRID);                     // 2000 blocks (sweep + zero)
    dim3 scg(SGRID + CGRID);                     // 1800 blocks (sweep + cand)
    dim3 pb(256), pg(NVOX / 4 / 256);            // 4000 blocks (proba x4)

    // g1..g3: sweeps fused with the 3 independent cw int-rotate passes.
    // Sweeps ping-pong W2 -> W4 -> W2 (W4 = idle cnt region); rotates
    // data -> W1 -> W3 -> W1 (cwp ends in W1).
    sweep_rot_kernel<0><<<srg, sbk, 0, stream>>>(data, nullptr, (int*)W2,
                                                 data, (unsigned*)W1);       // g1 | rot1
    sweep_rot_kernel<1><<<srg, sbk, 0, stream>>>(nullptr, (int*)W2, W4,
                                                 W1, (unsigned*)W3);         // g2 | rot2
    sweep_rot_kernel<1><<<srg, sbk, 0, stream>>>(nullptr, W4, (int*)W2,
                                                 W3, (unsigned*)W1);         // g3 | rot3
    unsigned* cwp = (unsigned*)W1;               // original layout

    // g4: sweep fused with zeroing cnt + tickets (W4 dead after g3 read it).
    sweep_zero_kernel<<<szg, sbk, 0, stream>>>((int*)W2, (int*)W3, W4, tickets); // g4

    // g5: sweep fused with the cand rider (cand = f(cwp) only).
    sweep_cand_kernel<<<scg, sbk, 0, stream>>>((int*)W3, (int*)W2, cwp, cand);   // g5

    // g6..g15: plain sweeps, W2 <-> W3 ping-pong (g15 ends in W2).
    for (int i = 0; i < 10; ++i) {
        const int* src = (i & 1) ? (int*)W3 : (int*)W2;
        int*       dst = (i & 1) ? (int*)W2 : (int*)W3;
        ccl_sweep_kernel<<<sg, sbk, 0, stream>>>(src, dst);
    }
    // g16: final sweep + component-size count into cnt (=W4, zeroed at g4).
    ccl_sweep_count_kernel<<<sg, sbk, 0, stream>>>((int*)W2, (int*)W3, cnt);
    int* lab = (int*)W3;                         // gen-16 labels

    // cs: fused z+y plane pass (gather inline) -> W2; then x-filter +
    // finalize (idx + histogram). W3/W4 become partial/idxbuf afterwards.
    plane_zy_g_kernel<<<dim3(D), dim3(256), 0, stream>>>(lab, cnt, cwp, W2);
    box_fin_x_kernel<<<dim3(FGRID), dim3(256), 0, stream>>>(W2, cwp, idxbuf, partial);

    hist_rp_kernel<<<dim3(16), dim3(256), 0, stream>>>(partial, hist, ph, Sv,
                                                       &tickets[0]);
    proba_kernel<<<pg, pb, 0, stream>>>(idxbuf, ph, Sv, proba);
}

// Round 7
// 388.555 us; speedup vs baseline: 1.2263x; 1.0140x over previous
//
#include <hip/hip_runtime.h>
#include <cmath>

#define D 160
#define DD (D*D)          // 25600
#define NVOX (D*D*D)
#define BIGV (NVOX + 2)
#define NBINS 4096
#define HALF 16
#define RGRID 800         // rotate-pass / fin blocks = DD/32, also hist partial count
#define SGRID 1000        // fused sweep blocks (512 thr, 8 cells/thread)
#define S2GRID 2000       // plain sweep blocks (256 thr, 8 cells/thread)
#define ZGRID 1000        // zero-cnt blocks fused into sweep 4
#define CGRID 800         // cand rider blocks fused into sweep 5

// ---------------------------------------------------------------------------
// COUNTER NOTE (R6 resolution): WRITE_SIZE's gfx94x-fallback formula
// mis-scales wide coalesced stores on gfx950 — plane_zy (scalar stores,
// 16.384 MB written) measured EXACTLY 16000 KiB while the sweeps (dwordx4,
// same 16.384 MB) measure 54137 KiB (3.3x, bit-identical across rounds).
// Sweep true traffic ~25 MB -> 4us floor vs ~10us real: sweeps are
// latency/ramp/drain-bound, not HBM-bound.
// ---------------------------------------------------------------------------

// ---------------------------------------------------------------------------
// Rotate box pass as a device block-function (512-thread mapping: 16 strips
// x 10 elems), riding inside sweep launches g1-g3 as extra blocks.
// MODE 0: pack classes from raw float data. MODE 1: pass-through uint.
// Layout (a,b,c) c-contig -> filter along c -> write (c,a,b).
// ---------------------------------------------------------------------------
template<int MODE>
__device__ __forceinline__ void rot_block(
    const void* __restrict__ vin, unsigned* __restrict__ out, int bi, int tid)
{
    __shared__ unsigned tin[32][161];
    __shared__ unsigned filt[160][33];
    int L0 = bi * 32;
    size_t base = (size_t)L0 * D;

    if (MODE == 0) {
        const float4* s4 = (const float4*)((const float*)vin + base);
        for (int i = tid; i < 32 * (D / 4); i += 512) {
            float4 v = s4[i];
            int e = i * 4, r = e / D, c = e - r * D;
            float rr;
            rr = rintf(v.x); tin[r][c]   = (rr==0.f) | ((rr==1.f)?0x10000u:0u);
            rr = rintf(v.y); tin[r][c+1] = (rr==0.f) | ((rr==1.f)?0x10000u:0u);
            rr = rintf(v.z); tin[r][c+2] = (rr==0.f) | ((rr==1.f)?0x10000u:0u);
            rr = rintf(v.w); tin[r][c+3] = (rr==0.f) | ((rr==1.f)?0x10000u:0u);
        }
    } else {
        const uint4* s4 = (const uint4*)((const unsigned*)vin + base);
        for (int i = tid; i < 32 * (D / 4); i += 512) {
            uint4 v = s4[i];
            int e = i * 4, r = e / D, c = e - r * D;
            tin[r][c] = v.x; tin[r][c+1] = v.y; tin[r][c+2] = v.z; tin[r][c+3] = v.w;
        }
    }
    __syncthreads();

    {
        int r = tid & 31, s = tid >> 5;      // s in [0,16)
        int i0 = 10 * s;
        const unsigned* ln = tin[r];
        unsigned sum = 0u;
        int jlo = i0 - 16; if (jlo < 0) jlo = 0;
        int jhi = i0 + 15; if (jhi > D - 1) jhi = D - 1;
        for (int j = jlo; j <= jhi; ++j) sum += ln[j];
        #pragma unroll
        for (int k = 0; k < 10; ++k) {
            int i = i0 + k;
            filt[i][r] = sum;
            int add = i + 16, rem = i - 16;
            if (add <= D - 1) sum += ln[add];
            if (rem >= 0)     sum -= ln[rem];
        }
    }
    __syncthreads();

    int r = tid & 31;
    for (int c = (tid >> 5); c < D; c += 16)
        out[(size_t)c * DD + L0 + r] = filt[c][r];
}

// ---------------------------------------------------------------------------
// Rotate box filter, FLOAT path, pass 1: fuses the lsize*valid gather.
// (R4-verified tail: absmax 0.0.)
// ---------------------------------------------------------------------------
__global__ __launch_bounds__(256) void box_rot_f32_g_kernel(
    const int* __restrict__ lab, const int* __restrict__ cnt,
    const unsigned* __restrict__ cwp, float* __restrict__ out)
{
    __shared__ float tin[32][161];
    __shared__ float filt[160][33];
    int L0 = blockIdx.x * 32;
    size_t base = (size_t)L0 * D;

    const int4*  lab4 = (const int4*)(lab + base);
    const uint4* cw4  = (const uint4*)(cwp + base);
    for (int i = threadIdx.x; i < 32 * (D / 4); i += 256) {
        int4 l = lab4[i];
        uint4 cw = cw4[i];
        int e = i * 4, r = e / D, c = e - r * D;
        tin[r][c]   = (l.x != BIGV && (cw.x >> 16) > 100u) ? (float)cnt[l.x] : 0.f;
        tin[r][c+1] = (l.y != BIGV && (cw.y >> 16) > 100u) ? (float)cnt[l.y] : 0.f;
        tin[r][c+2] = (l.z != BIGV && (cw.z >> 16) > 100u) ? (float)cnt[l.z] : 0.f;
        tin[r][c+3] = (l.w != BIGV && (cw.w >> 16) > 100u) ? (float)cnt[l.w] : 0.f;
    }
    __syncthreads();

    {
        int r = threadIdx.x & 31, s = threadIdx.x >> 5;
        int i0 = 20 * s;
        const float* ln = tin[r];
        float sum = 0.f;
        int jlo = i0 - 16; if (jlo < 0) jlo = 0;
        int jhi = i0 + 15; if (jhi > D - 1) jhi = D - 1;
        for (int j = jlo; j <= jhi; ++j) sum += ln[j];
        #pragma unroll 4
        for (int k = 0; k < 20; ++k) {
            int i = i0 + k;
            filt[i][r] = sum;
            int add = i + 16, rem = i - 16;
            if (add <= D - 1) sum += ln[add];
            if (rem >= 0)     sum -= ln[rem];
        }
    }
    __syncthreads();

    int r = threadIdx.x & 31;
    for (int c = (threadIdx.x >> 5); c < D; c += 8)
        out[(size_t)c * DD + L0 + r] = filt[c][r];
}

// plain float middle pass
__global__ __launch_bounds__(256) void box_rot_f32_kernel(
    const float* __restrict__ fin, float* __restrict__ out)
{
    __shared__ float tin[32][161];
    __shared__ float filt[160][33];
    int L0 = blockIdx.x * 32;
    size_t base = (size_t)L0 * D;

    const float4* s4 = (const float4*)(fin + base);
    for (int i = threadIdx.x; i < 32 * (D / 4); i += 256) {
        float4 v = s4[i];
        int e = i * 4, r = e / D, c = e - r * D;
        tin[r][c] = v.x; tin[r][c+1] = v.y; tin[r][c+2] = v.z; tin[r][c+3] = v.w;
    }
    __syncthreads();

    {
        int r = threadIdx.x & 31, s = threadIdx.x >> 5;
        int i0 = 20 * s;
        const float* ln = tin[r];
        float sum = 0.f;
        int jlo = i0 - 16; if (jlo < 0) jlo = 0;
        int jhi = i0 + 15; if (jhi > D - 1) jhi = D - 1;
        for (int j = jlo; j <= jhi; ++j) sum += ln[j];
        #pragma unroll 4
        for (int k = 0; k < 20; ++k) {
            int i = i0 + k;
            filt[i][r] = sum;
            int add = i + 16, rem = i - 16;
            if (add <= D - 1) sum += ln[add];
            if (rem >= 0)     sum -= ln[rem];
        }
    }
    __syncthreads();

    int r = threadIdx.x & 31;
    for (int c = (threadIdx.x >> 5); c < D; c += 8)
        out[(size_t)c * DD + L0 + r] = filt[c][r];
}

// ---------------------------------------------------------------------------
// cs pass 3 fused with finalize: idx + LDS histogram. (cand produced by the
// g5 rider; cd re-derived from cwp here.) hist reduce+post stays a separate
// kernel (R5 lesson: device-fence + cross-XCD consumer INSIDE a wide kernel
// costs ~90us; the kernel boundary is the cheap L2 flush).
// ---------------------------------------------------------------------------
__global__ __launch_bounds__(256) void box_rot_fin_kernel(
    const float* __restrict__ fin, const unsigned* __restrict__ cwp,
    unsigned short* __restrict__ idxbuf, int* __restrict__ partial)
{
    __shared__ float tin[32][161];
    __shared__ float filt[160][33];
    __shared__ int lh[NBINS];
    for (int i = threadIdx.x; i < NBINS; i += 256) lh[i] = 0;

    int L0 = blockIdx.x * 32;
    size_t base = (size_t)L0 * D;
    const float4* s4 = (const float4*)(fin + base);
    for (int i = threadIdx.x; i < 32 * (D / 4); i += 256) {
        float4 v = s4[i];
        int e = i * 4, r = e / D, c = e - r * D;
        tin[r][c] = v.x; tin[r][c+1] = v.y; tin[r][c+2] = v.z; tin[r][c+3] = v.w;
    }
    __syncthreads();

    {
        int r = threadIdx.x & 31, s = threadIdx.x >> 5;
        int i0 = 20 * s;
        const float* ln = tin[r];
        float sum = 0.f;
        int jlo = i0 - 16; if (jlo < 0) jlo = 0;
        int jhi = i0 + 15; if (jhi > D - 1) jhi = D - 1;
        for (int j = jlo; j <= jhi; ++j) sum += ln[j];
        #pragma unroll 4
        for (int k = 0; k < 20; ++k) {
            int i = i0 + k;
            filt[i][r] = sum;
            int add = i + 16, rem = i - 16;
            if (add <= D - 1) sum += ln[add];
            if (rem >= 0)     sum -= ln[rem];
        }
    }
    __syncthreads();

    int r = threadIdx.x & 31;
    int L = L0 + r;
    int y = L / D, z = L - (L / D) * D;
    bool byz = (y >= HALF && y < D - HALF && z >= HALF && z < D - HALF);
    int wy = min(y + 15, D - 1) - max(y - 16, 0) + 1;
    int wz = min(z + 15, D - 1) - max(z - 16, 0) + 1;
    for (int c = (threadIdx.x >> 5); c < D; c += 8) {   // c == x
        int p = c * DD + L;
        unsigned pk = cwp[p];
        unsigned cw0 = pk & 0xFFFFu;
        unsigned cw1 = pk >> 16;
        int wx = min(c + 15, D - 1) - max(c - 16, 0) + 1;
        unsigned cw2 = (unsigned)(wx * wy * wz) - cw0 - cw1;
        float v0 = (cw0 > 100u) ? 1.f : 0.f;
        float v1 = (cw1 > 100u) ? 1.f : 0.f;
        float v2 = (cw2 > 100u) ? 1.f : 0.f;
        float border = (byz && c >= HALF && c < D - HALF) ? 1.f : 0.f;
        float cd = (border * v1 + v0 + v2 >= 2.f) ? 1.f : 0.f;
        float mean = (cw1 > 0u) ? filt[c][r] / fmaxf((float)cw1, 1.f) : 0.f;
        int idx = (int)rintf(cd * mean);    // round half-to-even == jnp.round
        idx = min(max(idx, 0), NBINS - 1);
        idxbuf[p] = (unsigned short)idx;
        if (idx != 0) atomicAdd(&lh[idx], 1);   // hist[0] never consumed
    }
    __syncthreads();
    int* po = partial + blockIdx.x * NBINS;
    for (int i = threadIdx.x; i < NBINS; i += 256) po[i] = lh[i];
}

// ---------------------------------------------------------------------------
// CCL: 16 single-generation sweeps (R2: 2-gen register fusion = 3.5x a
// sweep, loses; 16 launches is the structure). R3: each launch slot costs
// ~6us wall -> riders fill idle sweep launches (g1-g3: cw rotate passes;
// g4: cnt+ticket zeroing; g5: cand). R6: sweeps proven latency/ramp-bound
// (WRITE_SIZE artifact resolved) -> g6-g16 move to 2000 x 256-thr blocks
// for finer scheduling granularity (8 resident blocks/CU, ~1.3us/block
// tail vs ~2.5us). Same contiguous half-wave chunk store pattern, same
// XCD 20-plane slabs (2000/8 = 250 blocks/XCD, bijective).
// ---------------------------------------------------------------------------
__device__ __forceinline__ int min6(int c, int a, int b, int d, int e, int f, int g) {
    if (c == BIGV) return BIGV;
    return min(min(min(c, a), min(b, d)), min(min(e, f), g));
}

__device__ __forceinline__ int4 min7_run(int4 c, int lm, int rm,
                                         int4 ym, int4 yp, int4 xm, int4 xp) {
    int4 o;
    o.x = min6(c.x, lm,  c.y, ym.x, yp.x, xm.x, xp.x);
    o.y = min6(c.y, c.x, c.z, ym.y, yp.y, xm.y, xp.y);
    o.z = min6(c.z, c.y, c.w, ym.z, yp.z, xm.z, xp.z);
    o.w = min6(c.w, c.z, rm,  ym.w, yp.w, xm.w, xp.w);
    return o;
}

__device__ __forceinline__ void wave_count(int l, int lane, int* __restrict__ cnt) {
    unsigned long long remaining = __ballot(l != BIGV);
    while (remaining) {
        int leader = __ffsll((unsigned long long)remaining) - 1;
        int ll = __shfl(l, leader, 64);
        unsigned long long mm = __ballot(l == ll);
        if (lane == leader) atomicAdd(&cnt[ll], (int)__popcll(mm & remaining));
        remaining &= ~mm;
    }
}

__device__ __forceinline__ int4 cls4(float4 v, int p0) {
    int4 l;
    l.x = (rintf(v.x) == 1.f) ? (p0 + 1) : BIGV;
    l.y = (rintf(v.y) == 1.f) ? (p0 + 2) : BIGV;
    l.z = (rintf(v.z) == 1.f) ? (p0 + 3) : BIGV;
    l.w = (rintf(v.w) == 1.f) ? (p0 + 4) : BIGV;
    return l;
}

struct LabLd {
    const int* __restrict__ a;
    __device__ __forceinline__ int4 v(int p) const { return ((const int4*)a)[p >> 2]; }
    __device__ __forceinline__ int  s(int p) const { return a[p]; }
};
struct DataLd {
    const float* __restrict__ a;
    __device__ __forceinline__ int4 v(int p) const { return cls4(((const float4*)a)[p >> 2], p); }
    __device__ __forceinline__ int  s(int p) const { return (rintf(a[p]) == 1.f) ? (p + 1) : BIGV; }
};

// Core: one generation for one wave's two contiguous 256-voxel chunks,
// starting at wbase (wave-uniform). Identical math for all geometries.
template<typename LDT, int COUNT>
__device__ __forceinline__ void sweep_core(
    LDT ld, int* __restrict__ outp, int* __restrict__ cnt, int wbase, int lane)
{
    const int4 BIG4 = make_int4(BIGV, BIGV, BIGV, BIGV);
    int pA = wbase + 4 * lane;
    int pB = pA + 256;

    int4 cA = ld.v(pA), cB = ld.v(pB);

    int zA = pA % D, zB = pB % D;
    int lmA = __shfl_up(cA.w, 1);
    int rmA = __shfl_down(cA.x, 1);
    int lmB = __shfl_up(cB.w, 1);
    int rmB = __shfl_down(cB.x, 1);
    int stA = __shfl(cB.x, 0, 64);   // voxel wbase+256 (A.lane63 right nbr)
    int stB = __shfl(cA.w, 63, 64);  // voxel wbase+255 (B.lane0 left nbr)
    if (lane == 63) rmA = stA;
    if (lane == 0)  lmB = stB;
    if (zA == 0)          lmA = BIGV;
    else if (lane == 0)   lmA = ld.s(pA - 1);
    if (zA == D - 4)      rmA = BIGV;
    if (zB == 0)          lmB = BIGV;
    if (zB == D - 4)      rmB = BIGV;
    else if (lane == 63)  rmB = ld.s(pB + 4);

    int rA = pA / D, yA = rA % D, xA = rA / D;
    int4 ylA = (yA > 0)     ? ld.v(pA - D)  : BIG4;
    int4 yhA = (yA < D - 1) ? ld.v(pA + D)  : BIG4;
    int4 xlA = (xA > 0)     ? ld.v(pA - DD) : BIG4;
    int4 xhA = (xA < D - 1) ? ld.v(pA + DD) : BIG4;
    int4 oA = min7_run(cA, lmA, rmA, ylA, yhA, xlA, xhA);

    int rB = pB / D, yB = rB % D, xB = rB / D;
    int4 ylB = (yB > 0)     ? ld.v(pB - D)  : BIG4;
    int4 yhB = (yB < D - 1) ? ld.v(pB + D)  : BIG4;
    int4 xlB = (xB > 0)     ? ld.v(pB - DD) : BIG4;
    int4 xhB = (xB < D - 1) ? ld.v(pB + DD) : BIG4;
    int4 oB = min7_run(cB, lmB, rmB, ylB, yhB, xlB, xhB);

    int4* out4 = (int4*)outp;
    out4[pA >> 2] = oA; out4[pB >> 2] = oB;

    if (COUNT) {   // final generation: component-size count from registers
        wave_count(oA.x, lane, cnt);
        wave_count(oA.y, lane, cnt);
        wave_count(oA.z, lane, cnt);
        wave_count(oA.w, lane, cnt);
        wave_count(oB.x, lane, cnt);
        wave_count(oB.y, lane, cnt);
        wave_count(oB.z, lane, cnt);
        wave_count(oB.w, lane, cnt);
    }
}

// old geometry (512 thr, SGRID blocks) for the fused rider launches g1-g5
template<typename LDT, int COUNT>
__device__ __forceinline__ void sweep_block512(
    LDT ld, int* __restrict__ outp, int* __restrict__ cnt, int b, int tid)
{
    int sb = (b & 7) * (SGRID / 8) + (b >> 3);   // XCD-contiguous x-slab
    int wbase = sb * 4096 + (tid >> 6) * 512;
    sweep_core<LDT, COUNT>(ld, outp, cnt, wbase, tid & 63);
}

// plain sweeps g6..g15: 256 thr x 2000 blocks (fine-grained scheduling)
__global__ __launch_bounds__(256) void ccl_sweep_kernel(
    const int* __restrict__ lab, int* __restrict__ outp)
{
    int b = blockIdx.x;
    int sb = (b & 7) * (S2GRID / 8) + (b >> 3);  // 250 blocks/XCD, bijective
    int wbase = sb * 2048 + ((int)threadIdx.x >> 6) * 512;
    LabLd ld{lab};
    sweep_core<LabLd, 0>(ld, outp, nullptr, wbase, threadIdx.x & 63);
}

// final sweep (g16) + component-size count, same fine geometry
__global__ __launch_bounds__(256) void ccl_sweep_count_kernel(
    const int* __restrict__ lab, int* __restrict__ outp, int* __restrict__ cnt)
{
    int b = blockIdx.x;
    int sb = (b & 7) * (S2GRID / 8) + (b >> 3);
    int wbase = sb * 2048 + ((int)threadIdx.x >> 6) * 512;
    LabLd ld{lab};
    sweep_core<LabLd, 1>(ld, outp, cnt, wbase, threadIdx.x & 63);
}

// sweep + rotate pass fused (g1..g3). MODE0: sweep from data + rot pass1
// (pack classes from data). MODE1: sweep from labels + rot pass-through.
template<int MODE>
__global__ __launch_bounds__(512) void sweep_rot_kernel(
    const float* __restrict__ data, const int* __restrict__ labsrc,
    int* __restrict__ swdst,
    const void* __restrict__ rin, unsigned* __restrict__ rout)
{
    if ((int)blockIdx.x < SGRID) {
        if (MODE == 0) {
            DataLd ld{data};
            sweep_block512<DataLd, 0>(ld, swdst, nullptr, blockIdx.x, threadIdx.x);
        } else {
            LabLd ld{labsrc};
            sweep_block512<LabLd, 0>(ld, swdst, nullptr, blockIdx.x, threadIdx.x);
        }
    } else {
        rot_block<MODE>(rin, rout, blockIdx.x - SGRID, threadIdx.x);
    }
}

// sweep g4 + zero the cnt region and the tickets (W4 dead after g3 read
// it; must be zero before g16's atomics). Replaces the upfront memset.
__global__ __launch_bounds__(512) void sweep_zero_kernel(
    const int* __restrict__ labsrc, int* __restrict__ swdst,
    int* __restrict__ zbuf, int* __restrict__ tickets)
{
    if ((int)blockIdx.x < SGRID) {
        LabLd ld{labsrc};
        sweep_block512<LabLd, 0>(ld, swdst, nullptr, blockIdx.x, threadIdx.x);
    } else {
        int zb = blockIdx.x - SGRID;                 // 0..ZGRID-1
        int t = (zb * 512 + threadIdx.x) * 2;        // int4 units
        const int4 z4 = make_int4(0, 0, 0, 0);
        ((int4*)zbuf)[t] = z4; ((int4*)zbuf)[t + 1] = z4;   // 1000*512*8 = NVOX ints
        if (zb == 0 && threadIdx.x == 0) {
            zbuf[NVOX] = 0; tickets[0] = 0; tickets[1] = 0;
        }
    }
}

// sweep g5 + cand rider: candidates depend only on cwp (ready after g3).
__global__ __launch_bounds__(512) void sweep_cand_kernel(
    const int* __restrict__ labsrc, int* __restrict__ swdst,
    const unsigned* __restrict__ cwp, float* __restrict__ cand)
{
    if ((int)blockIdx.x < SGRID) {
        LabLd ld{labsrc};
        sweep_block512<LabLd, 0>(ld, swdst, nullptr, blockIdx.x, threadIdx.x);
        return;
    }
    int t0 = (blockIdx.x - SGRID) * 512 + threadIdx.x;
    const uint4* cw4 = (const uint4*)cwp;
    float4* c4 = (float4*)cand;
    for (int q = t0; q < NVOX / 4; q += CGRID * 512) {
        int p0 = q * 4;
        int z0 = p0 % D;
        int r  = p0 / D;
        int y  = r % D;
        int x  = r / D;
        int wy = min(y + 15, D - 1) - max(y - 16, 0) + 1;
        int wx = min(x + 15, D - 1) - max(x - 16, 0) + 1;
        bool bxy = (y >= HALF && y < D - HALF && x >= HALF && x < D - HALF);
        uint4 pk = cw4[q];
        float4 o;
        {
            unsigned c0 = pk.x & 0xFFFFu, c1 = pk.x >> 16;
            int z = z0, wz = min(z + 15, D - 1) - max(z - 16, 0) + 1;
            unsigned c2 = (unsigned)(wx * wy * wz) - c0 - c1;
            float v0 = (c0 > 100u) ? 1.f : 0.f, v1 = (c1 > 100u) ? 1.f : 0.f, v2 = (c2 > 100u) ? 1.f : 0.f;
            float border = (bxy && z >= HALF && z < D - HALF) ? 1.f : 0.f;
            o.x = (border * v1 + v0 + v2 >= 2.f) ? 1.f : 0.f;
        }
        {
            unsigned c0 = pk.y & 0xFFFFu, c1 = pk.y >> 16;
            int z = z0 + 1, wz = min(z + 15, D - 1) - max(z - 16, 0) + 1;
            unsigned c2 = (unsigned)(wx * wy * wz) - c0 - c1;
            float v0 = (c0 > 100u) ? 1.f : 0.f, v1 = (c1 > 100u) ? 1.f : 0.f, v2 = (c2 > 100u) ? 1.f : 0.f;
            float border = (bxy && z >= HALF && z < D - HALF) ? 1.f : 0.f;
            o.y = (border * v1 + v0 + v2 >= 2.f) ? 1.f : 0.f;
        }
        {
            unsigned c0 = pk.z & 0xFFFFu, c1 = pk.z >> 16;
            int z = z0 + 2, wz = min(z + 15, D - 1) - max(z - 16, 0) + 1;
            unsigned c2 = (unsigned)(wx * wy * wz) - c0 - c1;
            float v0 = (c0 > 100u) ? 1.f : 0.f, v1 = (c1 > 100u) ? 1.f : 0.f, v2 = (c2 > 100u) ? 1.f : 0.f;
            float border = (bxy && z >= HALF && z < D - HALF) ? 1.f : 0.f;
            o.z = (border * v1 + v0 + v2 >= 2.f) ? 1.f : 0.f;
        }
        {
            unsigned c0 = pk.w & 0xFFFFu, c1 = pk.w >> 16;
            int z = z0 + 3, wz = min(z + 15, D - 1) - max(z - 16, 0) + 1;
            unsigned c2 = (unsigned)(wx * wy * wz) - c0 - c1;
            float v0 = (c0 > 100u) ? 1.f : 0.f, v1 = (c1 > 100u) ? 1.f : 0.f, v2 = (c2 > 100u) ? 1.f : 0.f;
            float border = (bxy && z >= HALF && z < D - HALF) ? 1.f : 0.f;
            o.w = (border * v1 + v0 + v2 >= 2.f) ? 1.f : 0.f;
        }
        c4[q] = o;
    }
}

// ---------------------------------------------------------------------------
// hist reduce + post fused via last-block ticket (separate kernel AFTER
// fin's kernel-end L2 flush — the safe structure per R5).
// ---------------------------------------------------------------------------
__global__ __launch_bounds__(256) void hist_rp_kernel(
    const int* __restrict__ partial, int* __restrict__ hist,
    float* __restrict__ ph_full, float* __restrict__ Sout,
    int* __restrict__ ticket)
{
    int t = threadIdx.x;
    int bin = blockIdx.x * 256 + t;     // 16 x 256 = 4096
    int s = 0;
    #pragma unroll 4
    for (int b = 0; b < RGRID; ++b) s += partial[b * NBINS + bin];
    __hip_atomic_store(&hist[bin], s, __ATOMIC_RELAXED, __HIP_MEMORY_SCOPE_AGENT);
    __threadfence();
    __syncthreads();
    __shared__ int lastblk;
    if (t == 0) lastblk = (atomicAdd(ticket, 1) == gridDim.x - 1) ? 1 : 0;
    __syncthreads();
    if (!lastblk) return;

    // ---- post phase (one block), bit-identical arithmetic to hist_post ----
    __shared__ float red[256];
    int hv[16];
    #pragma unroll
    for (int k = 0; k < 16; ++k)
        hv[k] = __hip_atomic_load(&hist[t + k * 256], __ATOMIC_RELAXED,
                                  __HIP_MEMORY_SCOPE_AGENT);

    float loc = 0.f;
    #pragma unroll
    for (int k = 0; k < 16; ++k) {
        int b = t + k * 256;
        if (b >= 1) loc += (float)hv[k];
    }
    red[t] = loc; __syncthreads();
    for (int o = 128; o > 0; o >>= 1) { if (t < o) red[t] += red[t + o]; __syncthreads(); }
    float numb = red[0]; __syncthreads();

    float rv[16];
    loc = 0.f;
    #pragma unroll
    for (int k = 0; k < 16; ++k) {
        int b = t + k * 256;
        float r = 0.f;
        if (b >= 1) {
            int h = hv[k];
            if (h > 0) r = numb / (float)h;
        }
        rv[k] = r;
        loc += r;
    }
    red[t] = loc; __syncthreads();
    for (int o = 128; o > 0; o >>= 1) { if (t < o) red[t] += red[t + o]; __syncthreads(); }
    float sumrec = red[0]; __syncthreads();
    float inv_sumrec = (sumrec > 0.f) ? 1.f / sumrec : 0.f;

    loc = 0.f;
    #pragma unroll
    for (int k = 0; k < 16; ++k) {
        int b = t + k * 256;
        float ph = (b >= 1) ? rv[k] * inv_sumrec : 0.f;
        ph_full[b] = ph;
        loc += ph * (float)hv[k];
    }
    red[t] = loc; __syncthreads();
    for (int o = 128; o > 0; o >>= 1) { if (t < o) red[t] += red[t + o]; __syncthreads(); }
    if (t == 0) Sout[0] = (red[0] > 0.f) ? red[0] : 1.f;
}

__global__ __launch_bounds__(256) void proba_kernel(
    const unsigned short* __restrict__ idxbuf,
    const float* __restrict__ ph_full, const float* __restrict__ Sv,
    float* __restrict__ outp)
{
    int t = blockIdx.x * blockDim.x + threadIdx.x;   // exact grid NVOX/4
    ushort4 i4 = ((const ushort4*)idxbuf)[t];
    float inv = 1.f / Sv[0];
    float4 o;
    o.x = ph_full[i4.x] * inv;
    o.y = ph_full[i4.y] * inv;
    o.z = ph_full[i4.z] * inv;
    o.w = ph_full[i4.w] * inv;
    ((float4*)outp)[t] = o;
}

// ---------------------------------------------------------------------------
extern "C" void kernel_launch(void* const* d_in, const int* in_sizes, int n_in,
                              void* d_out, int out_size, void* d_ws, size_t ws_size,
                              hipStream_t stream)
{
    const float* data = (const float*)d_in[0];
    float* out   = (float*)d_out;
    float* cand  = out;
    float* proba = out + NVOX;

    char* ws = (char*)d_ws;
    const size_t NB = (size_t)NVOX * sizeof(float);
    float* W1 = (float*)(ws);
    float* W2 = (float*)(ws + NB);
    float* W3 = (float*)(ws + 2 * NB);
    int*   W4 = (int*)(ws + 3 * NB);                   // cnt region / 3rd ping-pong buf
    int*   cnt  = W4;                                  // NVOX+1 ints (last int in pad)
    float* ph   = (float*)(ws + 4 * NB + 16);
    int*   hist = (int*)  (ws + 4 * NB + 16 + NBINS * 4);
    float* Sv   = (float*)(ws + 4 * NB + 16 + 2 * NBINS * 4);
    int*   tickets = (int*)(ws + 4 * NB + 16 + 2 * NBINS * 4 + 8);
    unsigned short* idxbuf = (unsigned short*)cnt;     // cnt dead after cs pass 1
    int* partial = (int*)W2;                           // W2 dead after cs pass 2

    dim3 rb(256), rg(RGRID);                     // 800 blocks (float rotate passes)
    dim3 sbk(512);
    dim3 s2bk(256), s2g(S2GRID);                 // 2000 blocks (plain sweeps)
    dim3 srg(SGRID + RGRID);                     // 1800 blocks (sweep + rotate)
    dim3 szg(SGRID + ZGRID);                     // 2000 blocks (sweep + zero)
    dim3 scg(SGRID + CGRID);                     // 1800 blocks (sweep + cand)
    dim3 pb(256), pg(NVOX / 4 / 256);            // 4000 blocks (proba x4)

    // g1..g3: sweeps fused with the 3 independent cw int-rotate passes.
    // Sweeps ping-pong W2 -> W4 -> W2 (W4 = idle cnt region); rotates
    // data -> W1 -> W3 -> W1 (cwp ends in W1).
    sweep_rot_kernel<0><<<srg, sbk, 0, stream>>>(data, nullptr, (int*)W2,
                                                 data, (unsigned*)W1);       // g1 | rot1
    sweep_rot_kernel<1><<<srg, sbk, 0, stream>>>(nullptr, (int*)W2, W4,
                                                 W1, (unsigned*)W3);         // g2 | rot2
    sweep_rot_kernel<1><<<srg, sbk, 0, stream>>>(nullptr, W4, (int*)W2,
                                                 W3, (unsigned*)W1);         // g3 | rot3
    unsigned* cwp = (unsigned*)W1;               // original layout

    // g4: sweep fused with zeroing cnt + tickets (W4 dead after g3 read it).
    sweep_zero_kernel<<<szg, sbk, 0, stream>>>((int*)W2, (int*)W3, W4, tickets); // g4

    // g5: sweep fused with the cand rider (cand = f(cwp) only).
    sweep_cand_kernel<<<scg, sbk, 0, stream>>>((int*)W3, (int*)W2, cwp, cand);   // g5

    // g6..g15: plain sweeps (fine geometry), W2 <-> W3 ping-pong (g15 -> W2).
    for (int i = 0; i < 10; ++i) {
        const int* src = (i & 1) ? (int*)W3 : (int*)W2;
        int*       dst = (i & 1) ? (int*)W2 : (int*)W3;
        ccl_sweep_kernel<<<s2g, s2bk, 0, stream>>>(src, dst);
    }
    // g16: final sweep + component-size count into cnt (=W4, zeroed at g4).
    ccl_sweep_count_kernel<<<s2g, s2bk, 0, stream>>>((int*)W2, (int*)W3, cnt);
    int* lab = (int*)W3;                         // gen-16 labels

    // cs float box sums (R4-verified tail: pass 1 fuses lsize*valid gather;
    // pass 3 fuses finalize: idx + histogram; hist reduce+post separate)
    box_rot_f32_g_kernel<<<rg, rb, 0, stream>>>(lab, cnt, cwp, W2);
    box_rot_f32_kernel<<<rg, rb, 0, stream>>>(W2, W3);
    box_rot_fin_kernel<<<rg, rb, 0, stream>>>(W3, cwp, idxbuf, partial);

    hist_rp_kernel<<<dim3(16), dim3(256), 0, stream>>>(partial, hist, ph, Sv,
                                                       &tickets[0]);
    proba_kernel<<<pg, pb, 0, stream>>>(idxbuf, ph, Sv, proba);
}